// Round 8
// baseline (361.113 us; speedup 1.0000x reference)
//
#include <hip/hip_runtime.h>
#include <cstdint>

#define B_    64
#define NV_   6890
#define NF_   13776
#define NHD_  20000
#define NP_   24
#define NCH   216           // ceil(6890/32) k-chunks of 32
#define BUF_HW 6144         // halfwords per LDS buffer (12 tiles * 64 lanes * 8) = 12 KB

// ---------------- workspace layout (bytes) ----------------
#define OFF_PPV   0u        // ppv [64][24] f32   6144   (zeroed by k_init)
#define OFF_RED   6144u     // red [64][6]  f32   1536   (zeroed by k_init)
#define OFF_VC    7680u     // Vc [216][12][64][8] bf16 = 2,654,208 B (fully rewritten)

typedef __attribute__((ext_vector_type(8))) __bf16 bf16x8;
typedef __attribute__((ext_vector_type(4))) float f32x4;

__device__ __forceinline__ unsigned short f2bf(float f) {
    unsigned u = __float_as_uint(f);
    u = (u + 0x7fffu + ((u >> 16) & 1u)) >> 16;   // RNE (no NaNs here)
    return (unsigned short)u;
}

// ---------------- K_init: zero ppv + red ----------------
__global__ __launch_bounds__(256) void k_init(float* __restrict__ z) {
    for (int i = threadIdx.x; i < 1920; i += 256) z[i] = 0.f;   // 1536 ppv + 384 red
}

// ---------------- K0v: pack V into MFMA-fragment order ----------------
// Vc[((c*12 + t)*64 + lane)*8 + j] = V_bf16[bd = t*16 + (lane&15)][k = c*32 + (lane>>4)*8 + j]
__global__ __launch_bounds__(256) void k0v_pack(const float* __restrict__ verts,
                                                unsigned short* __restrict__ Vc) {
    int idx = blockIdx.x * 256 + threadIdx.x;       // 216*12*512 = 1,327,104 total
    int j    = idx & 7;
    int lane = (idx >> 3) & 63;
    int ct   = idx >> 9;                            // c*12 + t
    int t    = ct % 12;
    int c    = ct / 12;
    int lm   = lane & 15;
    int kk   = (lane >> 4) * 8 + j;
    int bd   = t * 16 + lm;
    int d    = bd >> 6, b = bd & 63;
    int k    = c * 32 + kk;
    float v  = (k < NV_) ? verts[((size_t)b * NV_ + k) * 3 + d] : 0.f;
    Vc[idx] = f2bf(v);
}

// ---------------- K1: per-part volumes ----------------
__global__ __launch_bounds__(256) void k1_vol(const float* __restrict__ verts,
                                              const int* __restrict__ faces,
                                              const int* __restrict__ face_part,
                                              float* __restrict__ ppv) {
    __shared__ float bins[NP_];
    int b = blockIdx.y;
    int f = blockIdx.x * 256 + threadIdx.x;
    if (threadIdx.x < NP_) bins[threadIdx.x] = 0.f;
    __syncthreads();
    if (f < NF_) {
        int i0 = faces[3 * f], i1 = faces[3 * f + 1], i2 = faces[3 * f + 2];
        const float* vb = verts + (size_t)b * NV_ * 3;
        float ax = vb[3 * i0], ay = vb[3 * i0 + 1], az = vb[3 * i0 + 2];
        float bx = vb[3 * i1], by = vb[3 * i1 + 1], bz = vb[3 * i1 + 2];
        float cx = vb[3 * i2], cy = vb[3 * i2 + 1], cz = vb[3 * i2 + 2];
        float crx = by * cz - bz * cy;
        float cry = bz * cx - bx * cz;
        float crz = bx * cy - by * cx;
        float vol = fabsf(ax * crx + ay * cry + az * crz) * (1.0f / 6.0f);
        atomicAdd(&bins[face_part[f]], vol);
    }
    __syncthreads();
    if (threadIdx.x < NP_) atomicAdd(&ppv[b * NP_ + threadIdx.x], bins[threadIdx.x]);
}

// ---------------- KF: 1 wave/block, 32 rows, LDS dbuf, 2-phase vmcnt(0) schedule ---------
// Per chunk: s_waitcnt vmcnt(0)  [stage(c) + A(c) landed, both issued one iter earlier]
//            -> cvt A(c) -> issue stage(c+1) + loadA(c+1) -> ds_read Bu(c) -> 24 MFMA.
// Count-free: correctness does not depend on how the compiler merges the A loads.
__global__ __launch_bounds__(64) void kf_fused(const float* __restrict__ Hm,
                                               const unsigned short* __restrict__ Vc,
                                               const int* __restrict__ vert_fid,
                                               const int* __restrict__ face_part,
                                               const float* __restrict__ ppv,
                                               float* __restrict__ red) {
    __shared__ unsigned short Vl[2 * BUF_HW];       // 24 KB, wave-private double buffer
    const int lane = threadIdx.x;                   // 0..63
    const int lm   = lane & 15;
    const int kg   = lane >> 4;
    const int n0   = blockIdx.x * 32;
    const float* Arow0 = Hm + (size_t)(n0 + lm) * NV_;
    const float* Arow1 = Hm + (size_t)(n0 + 16 + lm) * NV_;

    f32x4 acc0[12], acc1[12];
#pragma unroll
    for (int t = 0; t < 12; ++t) {
        acc0[t] = (f32x4){0.f, 0.f, 0.f, 0.f};
        acc1[t] = (f32x4){0.f, 0.f, 0.f, 0.f};
    }

    auto stage = [&](int cc, unsigned short* dst) {
        const unsigned short* src = Vc + (size_t)cc * BUF_HW + lane * 8;
#pragma unroll
        for (int i = 0; i < 12; ++i)
            __builtin_amdgcn_global_load_lds(
                (const __attribute__((address_space(1))) void*)(src + i * 512),
                (__attribute__((address_space(3))) void*)(dst + i * 512), 16, 0, 0);
    };
    auto loadA = [&](int cc, float2* ra, float2* rb) {
        int k0 = cc * 32 + kg * 8;
#pragma unroll
        for (int j = 0; j < 4; ++j) {
            ra[j] = *reinterpret_cast<const float2*>(Arow0 + k0 + 2 * j);
            rb[j] = *reinterpret_cast<const float2*>(Arow1 + k0 + 2 * j);
        }
    };

    // prologue: stage chunk 0, A(0) to regs
    stage(0, &Vl[0]);
    float2 a[4], b[4];
    loadA(0, a, b);

    int p = 0;
#pragma unroll 1
    for (int c = 0; c < NCH - 1; ++c) {
        // phase boundary: everything issued last iteration has landed
        asm volatile("s_waitcnt vmcnt(0)" ::: "memory");
        __builtin_amdgcn_sched_barrier(0);
        // consume A(c) into the MFMA fragment (frees a/b registers)
        bf16x8 Af0, Af1;
#pragma unroll
        for (int j = 0; j < 4; ++j) {
            Af0[2 * j]     = (__bf16)a[j].x;
            Af0[2 * j + 1] = (__bf16)a[j].y;
            Af1[2 * j]     = (__bf16)b[j].x;
            Af1[2 * j + 1] = (__bf16)b[j].y;
        }
        __builtin_amdgcn_sched_barrier(0);
        // issue next chunk's loads early: in flight across ds_read + MFMAs
        stage(c + 1, &Vl[(p ^ 1) * BUF_HW]);
        int cpf = (c + 1 < NCH - 1) ? (c + 1) : (NCH - 2);
        loadA(cpf, a, b);                           // WAR on a/b after cvt: safe
        __builtin_amdgcn_sched_barrier(0);
        // ds_read current chunk's 12 B fragments (stage(c) landed at top)
        bf16x8 Bu[12];
        const unsigned short* bp = &Vl[p * BUF_HW] + lane * 8;
#pragma unroll
        for (int t = 0; t < 12; ++t)
            Bu[t] = *reinterpret_cast<const bf16x8*>(bp + t * 512);
#pragma unroll
        for (int t = 0; t < 12; ++t)
            acc0[t] = __builtin_amdgcn_mfma_f32_16x16x32_bf16(Af0, Bu[t], acc0[t], 0, 0, 0);
#pragma unroll
        for (int t = 0; t < 12; ++t)
            acc1[t] = __builtin_amdgcn_mfma_f32_16x16x32_bf16(Af1, Bu[t], acc1[t], 0, 0, 0);
        p ^= 1;
    }

    // ---- tail chunk 215 (staged by last main iter into Vl[p]); A guarded ----
    {
        asm volatile("s_waitcnt vmcnt(0)" ::: "memory");
        __builtin_amdgcn_sched_barrier(0);
        bf16x8 Bu[12];
        const unsigned short* bp = &Vl[p * BUF_HW] + lane * 8;
#pragma unroll
        for (int t = 0; t < 12; ++t)
            Bu[t] = *reinterpret_cast<const bf16x8*>(bp + t * 512);
        int k0 = (NCH - 1) * 32 + kg * 8;
        bf16x8 Af0, Af1;
#pragma unroll
        for (int j = 0; j < 8; ++j) {
            int k = k0 + j;
            float fa = (k < NV_) ? Arow0[k] : 0.f;
            float fb = (k < NV_) ? Arow1[k] : 0.f;
            Af0[j] = (__bf16)fa;
            Af1[j] = (__bf16)fb;
        }
#pragma unroll
        for (int t = 0; t < 12; ++t)
            acc0[t] = __builtin_amdgcn_mfma_f32_16x16x32_bf16(Af0, Bu[t], acc0[t], 0, 0, 0);
#pragma unroll
        for (int t = 0; t < 12; ++t)
            acc1[t] = __builtin_amdgcn_mfma_f32_16x16x32_bf16(Af1, Bu[t], acc1[t], 0, 0, 0);
    }

    // ---- epilogue: fully in-register. Lane owns rows {kg*4+r, 16+kg*4+r}, cols b=t*16+lm.
    // acc layout (verified): accX[t][r] = C[row][bd=t*16+lm]; x: t=0..3, h(y): t=4..7, z: t=8..11.
    int part0[4], part1[4];
#pragma unroll
    for (int r = 0; r < 4; ++r) {
        part0[r] = face_part[vert_fid[n0 + kg * 4 + r]];
        part1[r] = face_part[vert_fid[n0 + 16 + kg * 4 + r]];
    }
    float sums[4][6];                               // [t(b-group)][copx,copz,comx,comz,sp,sw]
#pragma unroll
    for (int t = 0; t < 4; ++t)
#pragma unroll
        for (int q = 0; q < 6; ++q) sums[t][q] = 0.f;

#pragma unroll
    for (int t = 0; t < 4; ++t) {
        int bcol = t * 16 + lm;
#pragma unroll
        for (int r = 0; r < 4; ++r) {
            {   // row group 0
                float x = acc0[t][r], h = acc0[4 + t][r], z = acc0[8 + t][r];
                float pwv = (h < 0.f) ? (1.f - 100.f * h) : expf(-10.f * h);
                float w = ppv[bcol * NP_ + part0[r]];
                sums[t][0] += pwv * x; sums[t][1] += pwv * z;
                sums[t][2] += w * x;   sums[t][3] += w * z;
                sums[t][4] += pwv;     sums[t][5] += w;
            }
            {   // row group 1
                float x = acc1[t][r], h = acc1[4 + t][r], z = acc1[8 + t][r];
                float pwv = (h < 0.f) ? (1.f - 100.f * h) : expf(-10.f * h);
                float w = ppv[bcol * NP_ + part1[r]];
                sums[t][0] += pwv * x; sums[t][1] += pwv * z;
                sums[t][2] += w * x;   sums[t][3] += w * z;
                sums[t][4] += pwv;     sums[t][5] += w;
            }
        }
    }
    // reduce across kg (lanes lm, lm+16, lm+32, lm+48 hold same b-set)
#pragma unroll
    for (int t = 0; t < 4; ++t)
#pragma unroll
        for (int q = 0; q < 6; ++q) {
            float v = sums[t][q];
            v += __shfl_xor(v, 16);
            v += __shfl_xor(v, 32);
            sums[t][q] = v;
        }
    if (kg == 0) {
#pragma unroll
        for (int t = 0; t < 4; ++t) {
            int bcol = t * 16 + lm;
#pragma unroll
            for (int q = 0; q < 6; ++q)
                atomicAdd(&red[bcol * 6 + q], sums[t][q]);
        }
    }
}

// ---------------- K5: finalize ----------------
__global__ __launch_bounds__(64) void k5_final(const float* __restrict__ red,
                                               float* __restrict__ out) {
    int b = threadIdx.x;
    if (b < B_) {
        float sp   = red[b * 6 + 4] + 1e-6f;
        float sw   = red[b * 6 + 5];
        float copx = red[b * 6 + 0] / sp;
        float copz = red[b * 6 + 1] / sp;
        float comx = red[b * 6 + 2] / sw;
        float comz = red[b * 6 + 3] / sw;
        float dx = comx - copx, dz = comz - copz;
        out[b] = sqrtf(dx * dx + dz * dz);
    }
}

extern "C" void kernel_launch(void* const* d_in, const int* in_sizes, int n_in,
                              void* d_out, int out_size, void* d_ws, size_t ws_size,
                              hipStream_t stream) {
    const float* verts     = (const float*)d_in[0];
    const float* Hm        = (const float*)d_in[1];
    const int*   faces     = (const int*)d_in[2];
    const int*   vert_fid  = (const int*)d_in[3];
    const int*   face_part = (const int*)d_in[4];
    char* ws = (char*)d_ws;
    float*          ppv = (float*)(ws + OFF_PPV);
    float*          red = (float*)(ws + OFF_RED);
    unsigned short* Vc  = (unsigned short*)(ws + OFF_VC);
    float* out = (float*)d_out;

    hipLaunchKernelGGL(k_init, dim3(1), dim3(256), 0, stream, (float*)ws);
    hipLaunchKernelGGL(k0v_pack, dim3((NCH * 12 * 512) / 256), dim3(256), 0, stream, verts, Vc);
    hipLaunchKernelGGL(k1_vol, dim3(54, 64), dim3(256), 0, stream, verts, faces, face_part, ppv);
    hipLaunchKernelGGL(kf_fused, dim3(NHD_ / 32), dim3(64), 0, stream,
                       Hm, Vc, vert_fid, face_part, ppv, red);
    hipLaunchKernelGGL(k5_final, dim3(1), dim3(64), 0, stream, red, out);
}